// Round 1
// baseline (761.796 us; speedup 1.0000x reference)
//
#include <hip/hip_runtime.h>

// Shapes: B=2, L=2048, D_MODEL=1024, H=16, D_K=64
// Pipeline:
//  1) gemm_proj<0/1/2>: Q/K/V = x @ W^T  (f32 in, f16 out, head-major [bh][l][64]).
//     Q is pre-scaled by 1/16 = (1/sqrt(64)) * (1/2)  [entmax z = scores/2, shift-invariant].
//  2) transpose_v: V [bh][l][64] -> Vt [bh][64][l]  (so PV B-fragments are contiguous).
//  3) attn_entmax: per block = 16 queries x 2048 keys, 8 waves (keys split 256/wave).
//     scores via mfma f16 -> f32 regs; exact 1.5-entmax via Newton (8 iters, monotone
//     from below on convex f(tau)=sum((z-tau)_+^2)) + closed-form support solve;
//     P -> swizzled LDS -> PV mfma; cross-wave reduce; AO f16 [b][l][1024].
//  4) gemm_proj<3>: out = AO @ Wo^T -> f32 d_out.

typedef _Float16 f16;
typedef __attribute__((ext_vector_type(8))) _Float16 f16x8;
typedef __attribute__((ext_vector_type(2))) _Float16 f16x2;
typedef __attribute__((ext_vector_type(4))) float f32x4;

// ---------------------------------------------------------------------------
// GEMM: C[M=4096, N=1024] = A[M,1024] * W[N=1024, K=1024]^T   (y = x @ W^T)
// MODE 0: Q (f16, *1/16, head-major)  1: K (f16 head-major)  2: V (f16 head-major)
// MODE 3: OUT (A is f16, C is f32 plain row-major)
// Tile: BM=128, BN=128, BK=32. 8 waves (4x2), wave tile 32x64, mfma 16x16x32 f16.
// ---------------------------------------------------------------------------
template <int MODE>
__global__ __launch_bounds__(512)
void gemm_proj(const void* __restrict__ Ap, const float* __restrict__ Wp,
               void* __restrict__ Cp)
{
    __shared__ __align__(16) f16 As[128 * 40];  // rows padded to 40 f16 (80 B)
    __shared__ __align__(16) f16 Bs[128 * 40];

    const int tid = threadIdx.x;
    const int mBase = blockIdx.x * 128;
    const int nBase = blockIdx.y * 128;

    const int lane = tid & 63, w = tid >> 6;
    const int g = lane >> 4, c = lane & 15;
    const int wm = w >> 1, wn = w & 1;          // 4x2 wave grid

    const int sr = tid >> 2;                    // staging row 0..127
    const int sq = tid & 3;                     // col group (8 f16 each)

    f32x4 acc[2][4];
    const f32x4 vzero = {0.f, 0.f, 0.f, 0.f};
#pragma unroll
    for (int i = 0; i < 2; i++)
#pragma unroll
        for (int j = 0; j < 4; j++) acc[i][j] = vzero;

    for (int k0 = 0; k0 < 1024; k0 += 32) {
        __syncthreads();
        // ---- stage A tile [128][32] ----
        {
            f16x8 av;
            if constexpr (MODE == 3) {
                const f16* A = (const f16*)Ap;
                av = *(const f16x8*)&A[(mBase + sr) * 1024 + k0 + sq * 8];
            } else {
                const float* A = (const float*)Ap;
                const float4* p = (const float4*)&A[(mBase + sr) * 1024 + k0 + sq * 8];
                float4 x0 = p[0], x1 = p[1];
                av[0] = (f16)x0.x; av[1] = (f16)x0.y; av[2] = (f16)x0.z; av[3] = (f16)x0.w;
                av[4] = (f16)x1.x; av[5] = (f16)x1.y; av[6] = (f16)x1.z; av[7] = (f16)x1.w;
            }
            *(f16x8*)&As[sr * 40 + sq * 8] = av;

            const float4* pw = (const float4*)&Wp[(nBase + sr) * 1024 + k0 + sq * 8];
            float4 w0 = pw[0], w1 = pw[1];
            f16x8 bv;
            bv[0] = (f16)w0.x; bv[1] = (f16)w0.y; bv[2] = (f16)w0.z; bv[3] = (f16)w0.w;
            bv[4] = (f16)w1.x; bv[5] = (f16)w1.y; bv[6] = (f16)w1.z; bv[7] = (f16)w1.w;
            *(f16x8*)&Bs[sr * 40 + sq * 8] = bv;
        }
        __syncthreads();

        f16x8 af[2], bf[4];
#pragma unroll
        for (int mt = 0; mt < 2; mt++)
            af[mt] = *(const f16x8*)&As[(wm * 32 + mt * 16 + c) * 40 + g * 8];
#pragma unroll
        for (int nt = 0; nt < 4; nt++)
            bf[nt] = *(const f16x8*)&Bs[(wn * 64 + nt * 16 + c) * 40 + g * 8];
#pragma unroll
        for (int mt = 0; mt < 2; mt++)
#pragma unroll
            for (int nt = 0; nt < 4; nt++)
                acc[mt][nt] = __builtin_amdgcn_mfma_f32_16x16x32_f16(af[mt], bf[nt], acc[mt][nt], 0, 0, 0);
    }

    // ---- epilogue ----
#pragma unroll
    for (int mt = 0; mt < 2; mt++)
#pragma unroll
        for (int nt = 0; nt < 4; nt++)
#pragma unroll
            for (int r = 0; r < 4; r++) {
                int row = mBase + wm * 32 + mt * 16 + g * 4 + r;   // C/D row = 4*(lane>>4)+reg
                int col = nBase + wn * 64 + nt * 16 + c;           // C/D col = lane&15
                float v = acc[mt][nt][r];
                if constexpr (MODE == 3) {
                    ((float*)Cp)[row * 1024 + col] = v;
                } else {
                    if constexpr (MODE == 0) v *= 0.0625f;         // 1/sqrt(64) * 1/2
                    int b = row >> 11, l = row & 2047;
                    int h = col >> 6, dk = col & 63;
                    ((f16*)Cp)[((b * 16 + h) * 2048 + l) * 64 + dk] = (f16)v;
                }
            }
}

// ---------------------------------------------------------------------------
// V [bh][2048][64] f16 -> Vt [bh][64][2048] f16
// ---------------------------------------------------------------------------
__global__ __launch_bounds__(256)
void transpose_v(const f16* __restrict__ V, f16* __restrict__ Vt)
{
    __shared__ f16 t[64][65];
    const int bh = blockIdx.y, lt = blockIdx.x;
    const int tid = threadIdx.x;
#pragma unroll
    for (int i = 0; i < 16; i++) {
        int idx = tid + 256 * i;           // 0..4095
        int r = idx >> 6, cc = idx & 63;
        t[r][cc] = V[(bh * 2048 + lt * 64 + r) * 64 + cc];
    }
    __syncthreads();
#pragma unroll
    for (int i = 0; i < 16; i++) {
        int idx = tid + 256 * i;
        int d = idx >> 6, lc = idx & 63;
        Vt[(bh * 64 + d) * 2048 + lt * 64 + lc] = t[lc][d];
    }
}

// ---------------------------------------------------------------------------
// Attention + exact 1.5-entmax.
// Block = 16 queries x 2048 keys, 8 waves; wave w owns keys [w*256, w*256+256).
// z = scores/2 is already in regs (Q pre-scaled by 1/16). tau solves
// sum((z - tau)_+^2) = 1  (shift-invariant wrt the reference's max-subtraction).
// ---------------------------------------------------------------------------
__global__ __launch_bounds__(512)
void attn_entmax(const f16* __restrict__ Q, const f16* __restrict__ Kh,
                 const f16* __restrict__ Vt, const int* __restrict__ mask,
                 f16* __restrict__ AO)
{
    __shared__ __align__(16) char Praw[16 * 4096];   // 64 KB: P[16][2048] f16, XOR-swizzled
    __shared__ float red[8][16][4];                  // cross-wave reduce buffer

    const int tid = threadIdx.x;
    const int w = tid >> 6, lane = tid & 63;
    const int g = lane >> 4, c = lane & 15;
    const int bh = blockIdx.y, b = bh >> 4, h = bh & 15;
    const int qb = blockIdx.x * 16;

    // Q A-fragments (rows = 16 queries, K-dim = 64 -> 2 mfma k-steps)
    f16x8 aq[2];
#pragma unroll
    for (int ks = 0; ks < 2; ks++)
        aq[ks] = *(const f16x8*)&Q[(bh * 2048 + qb + c) * 64 + ks * 32 + g * 8];

    // ---- scores: S[t] = 16x16 tile (q x key), t = key tile within wave slice ----
    f32x4 S[16];
#pragma unroll
    for (int t = 0; t < 16; t++) {
        int j0 = w * 256 + t * 16;
        f16x8 kf0 = *(const f16x8*)&Kh[(bh * 2048 + j0 + c) * 64 + g * 8];
        f16x8 kf1 = *(const f16x8*)&Kh[(bh * 2048 + j0 + c) * 64 + 32 + g * 8];
        f32x4 z = {0.f, 0.f, 0.f, 0.f};
        z = __builtin_amdgcn_mfma_f32_16x16x32_f16(aq[0], kf0, z, 0, 0, 0);
        z = __builtin_amdgcn_mfma_f32_16x16x32_f16(aq[1], kf1, z, 0, 0, 0);
        S[t] = z;
    }

    // ---- mask (mask==0 -> -inf surrogate) ----
#pragma unroll
    for (int t = 0; t < 16; t++) {
        int j = w * 256 + t * 16 + c;
#pragma unroll
        for (int r = 0; r < 4; r++) {
            int qrow = qb + g * 4 + r;
            if (mask[(b * 2048 + qrow) * 2048 + j] == 0) S[t][r] = -1e30f;
        }
    }

    // ---- row max (z is S; zmax per row) ----
    float zmax[4] = {-3e38f, -3e38f, -3e38f, -3e38f};
#pragma unroll
    for (int t = 0; t < 16; t++)
#pragma unroll
        for (int r = 0; r < 4; r++) zmax[r] = fmaxf(zmax[r], S[t][r]);
#pragma unroll
    for (int off = 8; off >= 1; off >>= 1)
#pragma unroll
        for (int r = 0; r < 4; r++) zmax[r] = fmaxf(zmax[r], __shfl_xor(zmax[r], off));
    if (c == 0) {
#pragma unroll
        for (int r = 0; r < 4; r++) red[w][g * 4 + r][0] = zmax[r];
    }
    __syncthreads();
#pragma unroll
    for (int r = 0; r < 4; r++) {
        float m = -3e38f;
#pragma unroll
        for (int ww = 0; ww < 8; ww++) m = fmaxf(m, red[ww][g * 4 + r][0]);
        zmax[r] = m;
    }
    __syncthreads();

    // ---- Newton from below: tau0 = zmax - 1, f(tau) = sum((z-tau)_+^2) ----
    float tau[4];
#pragma unroll
    for (int r = 0; r < 4; r++) tau[r] = zmax[r] - 1.0f;

    for (int it = 0; it < 8; ++it) {
        float s1[4] = {0.f, 0.f, 0.f, 0.f}, s2[4] = {0.f, 0.f, 0.f, 0.f};
#pragma unroll
        for (int t = 0; t < 16; t++)
#pragma unroll
            for (int r = 0; r < 4; r++) {
                float d = fmaxf(S[t][r] - tau[r], 0.f);
                s1[r] += d;
                s2[r] = fmaf(d, d, s2[r]);
            }
#pragma unroll
        for (int off = 8; off >= 1; off >>= 1)
#pragma unroll
            for (int r = 0; r < 4; r++) {
                s1[r] += __shfl_xor(s1[r], off);
                s2[r] += __shfl_xor(s2[r], off);
            }
        if (c == 0) {
#pragma unroll
            for (int r = 0; r < 4; r++) {
                red[w][g * 4 + r][0] = s1[r];
                red[w][g * 4 + r][1] = s2[r];
            }
        }
        __syncthreads();
#pragma unroll
        for (int r = 0; r < 4; r++) {
            float a = 0.f, f = 0.f;
#pragma unroll
            for (int ww = 0; ww < 8; ww++) {
                a += red[ww][g * 4 + r][0];
                f += red[ww][g * 4 + r][1];
            }
            if (a > 1e-12f)
                tau[r] = fminf(tau[r] + (f - 1.0f) / (2.0f * a), zmax[r] - 1e-3f);
        }
        __syncthreads();
    }

    // ---- closed-form refine over support {z > tau} (exact given support) ----
    {
        float kc[4] = {0.f, 0.f, 0.f, 0.f}, s1[4] = {0.f, 0.f, 0.f, 0.f}, s2[4] = {0.f, 0.f, 0.f, 0.f};
#pragma unroll
        for (int t = 0; t < 16; t++)
#pragma unroll
            for (int r = 0; r < 4; r++) {
                float d = S[t][r] - tau[r];
                if (d > 0.f) {
                    kc[r] += 1.f;
                    s1[r] += d;
                    s2[r] = fmaf(d, d, s2[r]);
                }
            }
#pragma unroll
        for (int off = 8; off >= 1; off >>= 1)
#pragma unroll
            for (int r = 0; r < 4; r++) {
                kc[r] += __shfl_xor(kc[r], off);
                s1[r] += __shfl_xor(s1[r], off);
                s2[r] += __shfl_xor(s2[r], off);
            }
        if (c == 0) {
#pragma unroll
            for (int r = 0; r < 4; r++) {
                red[w][g * 4 + r][0] = kc[r];
                red[w][g * 4 + r][1] = s1[r];
                red[w][g * 4 + r][2] = s2[r];
            }
        }
        __syncthreads();
#pragma unroll
        for (int r = 0; r < 4; r++) {
            float K_ = 0.f, a = 0.f, q2 = 0.f;
#pragma unroll
            for (int ww = 0; ww < 8; ww++) {
                K_ += red[ww][g * 4 + r][0];
                a += red[ww][g * 4 + r][1];
                q2 += red[ww][g * 4 + r][2];
            }
            K_ = fmaxf(K_, 1.0f);
            float disc = fmaxf(a * a - K_ * (q2 - 1.0f), 0.f);
            tau[r] += (a - sqrtf(disc)) / K_;   // smaller quadratic root
        }
        __syncthreads();
    }

    // ---- P = ((z - tau)_+)^2 -> f16 -> swizzled LDS ----
#pragma unroll
    for (int t = 0; t < 16; t++) {
        int col = w * 256 + t * 16 + c;
#pragma unroll
        for (int r = 0; r < 4; r++) {
            int row = g * 4 + r;
            float d = fmaxf(S[t][r] - tau[r], 0.f);
            int byte = (row << 12) + col * 2;
            byte ^= (row & 7) << 4;
            *(f16*)&Praw[byte] = (f16)(d * d);
        }
    }
    __syncthreads();

    // ---- PV: out[16 q][64 d] partial over this wave's key slice ----
    f32x4 O[4];
    const f32x4 vzero = {0.f, 0.f, 0.f, 0.f};
#pragma unroll
    for (int nd = 0; nd < 4; nd++) O[nd] = vzero;
#pragma unroll
    for (int s = 0; s < 8; s++) {
        int j0 = w * 256 + s * 32;
        int abyte = (c << 12) + (j0 + g * 8) * 2;
        abyte ^= (c & 7) << 4;
        f16x8 pa = *(const f16x8*)&Praw[abyte];      // A-frag: row=c, keys contiguous
#pragma unroll
        for (int nd = 0; nd < 4; nd++) {
            f16x8 vb = *(const f16x8*)&Vt[(bh * 64 + nd * 16 + c) * 2048 + j0 + g * 8];
            O[nd] = __builtin_amdgcn_mfma_f32_16x16x32_f16(pa, vb, O[nd], 0, 0, 0);
        }
    }
    __syncthreads();   // all P reads done; reuse Praw as f32 reduce buffer

    float* Ored = (float*)Praw;                      // [8][16][64] f32 = 32 KB
#pragma unroll
    for (int nd = 0; nd < 4; nd++)
#pragma unroll
        for (int r = 0; r < 4; r++)
            Ored[(w * 16 + g * 4 + r) * 64 + nd * 16 + c] = O[nd][r];
    __syncthreads();

    // final cross-wave sum + store AO f16 [b][l][h*64+d]
    const int qrow = tid >> 5;       // 0..15
    const int dp = tid & 31;         // 0..31 (pairs of d)
    float o0 = 0.f, o1 = 0.f;
#pragma unroll
    for (int ww = 0; ww < 8; ww++) {
        o0 += Ored[(ww * 16 + qrow) * 64 + dp * 2];
        o1 += Ored[(ww * 16 + qrow) * 64 + dp * 2 + 1];
    }
    f16x2 pk;
    pk[0] = (f16)o0;
    pk[1] = (f16)o1;
    *(f16x2*)&AO[(b * 2048 + qb + qrow) * 1024 + h * 64 + dp * 2] = pk;
}

// ---------------------------------------------------------------------------
extern "C" void kernel_launch(void* const* d_in, const int* in_sizes, int n_in,
                              void* d_out, int out_size, void* d_ws, size_t ws_size,
                              hipStream_t stream)
{
    const float* q  = (const float*)d_in[0];
    const float* k  = (const float*)d_in[1];
    const float* v  = (const float*)d_in[2];
    const int* mask = (const int*)d_in[3];
    const float* wq = (const float*)d_in[4];
    const float* wk = (const float*)d_in[5];
    const float* wv = (const float*)d_in[6];
    const float* wo = (const float*)d_in[7];

    char* ws = (char*)d_ws;
    const size_t SZ = 4194304ull * 2ull;  // 8 MB per f16 buffer (B*H*L*64 = B*L*DM)
    f16* Qb  = (f16*)(ws);
    f16* Kb  = (f16*)(ws + SZ);
    f16* Vb  = (f16*)(ws + 2 * SZ);
    f16* Vtb = (f16*)(ws + 3 * SZ);
    f16* AOb = (f16*)(ws + 4 * SZ);

    dim3 gg(32, 8);
    gemm_proj<0><<<gg, 512, 0, stream>>>(q, wq, Qb);
    gemm_proj<1><<<gg, 512, 0, stream>>>(k, wk, Kb);
    gemm_proj<2><<<gg, 512, 0, stream>>>(v, wv, Vb);
    transpose_v<<<dim3(32, 32), 256, 0, stream>>>(Vb, Vtb);
    attn_entmax<<<dim3(128, 32), 512, 0, stream>>>(Qb, Kb, Vtb, mask, AOb);
    gemm_proj<3><<<gg, 512, 0, stream>>>(AOb, wo, d_out);
}

// Round 2
// 507.182 us; speedup vs baseline: 1.5020x; 1.5020x over previous
//
#include <hip/hip_runtime.h>

// Shapes: B=2, L=2048, D_MODEL=1024, H=16, D_K=64
// Pipeline:
//  0) pack_mask: mask int32 [B][L][L] -> bit-packed u32 [B][L][L/32].
//  1) gemm_proj<0/1>: Q/K = x @ W^T (f32 in, f16 out, head-major [bh][l][64]).
//     Q pre-scaled by 1/16 = (1/sqrt(64)) * (1/2)  [entmax z = scores/2].
//  2) gemm_proj<2>: V projection, epilogue writes Vt [bh][64][l] directly.
//  3) attn_entmax: block = 16 queries x 2048 keys, 8 waves (256 keys/wave).
//     Swapped QK^T (mfma(K,Q)) -> S^T in regs: lane holds 64 scores of ONE query
//     (col=lane&15). Entmax tau via scalar Newton (8 iters, 1 barrier each,
//     double-buffered 2KB reduce) + closed-form support solve. PV directly from
//     registers via mfma_f32_16x16x16f16 (D-frag == B-frag layout), no P LDS.
//  4) gemm_proj<3>: out = AO @ Wo^T -> f32 d_out.

typedef _Float16 f16;
typedef __attribute__((ext_vector_type(8))) _Float16 f16x8;
typedef __attribute__((ext_vector_type(4))) _Float16 f16x4;
typedef __attribute__((ext_vector_type(2))) _Float16 f16x2;
typedef __attribute__((ext_vector_type(4))) float f32x4;
typedef unsigned int u32;

// ---------------------------------------------------------------------------
// mask [2][2048][2048] int -> bits [2][2048][64] u32 (bit j of word w = key w*32+j)
// ---------------------------------------------------------------------------
__global__ __launch_bounds__(256)
void pack_mask(const int* __restrict__ mask, u32* __restrict__ bits)
{
    int idx = blockIdx.x * 256 + threadIdx.x;        // 0..262143
    const int4* p = (const int4*)&mask[(size_t)idx * 32];
    u32 v = 0;
#pragma unroll
    for (int i = 0; i < 8; i++) {
        int4 m = p[i];
        if (m.x != 0) v |= 1u << (i * 4 + 0);
        if (m.y != 0) v |= 1u << (i * 4 + 1);
        if (m.z != 0) v |= 1u << (i * 4 + 2);
        if (m.w != 0) v |= 1u << (i * 4 + 3);
    }
    bits[idx] = v;
}

// ---------------------------------------------------------------------------
// GEMM: C[M=4096, N=1024] = A[M,1024] * W[N,K=1024]^T   (y = x @ W^T)
// MODE 0: Q (f16, *1/16, head-major [bh][l][64])
// MODE 1: K (f16 head-major)
// MODE 2: V -> writes Vt [bh][64][l] (transposed) directly
// MODE 3: OUT (A is f16, C is f32 row-major)
// ---------------------------------------------------------------------------
template <int MODE>
__global__ __launch_bounds__(512)
void gemm_proj(const void* __restrict__ Ap, const float* __restrict__ Wp,
               void* __restrict__ Cp)
{
    __shared__ __align__(16) f16 As[128 * 40];
    __shared__ __align__(16) f16 Bs[128 * 40];

    const int tid = threadIdx.x;
    const int mBase = blockIdx.x * 128;
    const int nBase = blockIdx.y * 128;

    const int lane = tid & 63, w = tid >> 6;
    const int g = lane >> 4, c = lane & 15;
    const int wm = w >> 1, wn = w & 1;

    const int sr = tid >> 2;
    const int sq = tid & 3;

    f32x4 acc[2][4];
    const f32x4 vzero = {0.f, 0.f, 0.f, 0.f};
#pragma unroll
    for (int i = 0; i < 2; i++)
#pragma unroll
        for (int j = 0; j < 4; j++) acc[i][j] = vzero;

    for (int k0 = 0; k0 < 1024; k0 += 32) {
        __syncthreads();
        {
            f16x8 av;
            if constexpr (MODE == 3) {
                const f16* A = (const f16*)Ap;
                av = *(const f16x8*)&A[(size_t)(mBase + sr) * 1024 + k0 + sq * 8];
            } else {
                const float* A = (const float*)Ap;
                const float4* p = (const float4*)&A[(size_t)(mBase + sr) * 1024 + k0 + sq * 8];
                float4 x0 = p[0], x1 = p[1];
                av[0] = (f16)x0.x; av[1] = (f16)x0.y; av[2] = (f16)x0.z; av[3] = (f16)x0.w;
                av[4] = (f16)x1.x; av[5] = (f16)x1.y; av[6] = (f16)x1.z; av[7] = (f16)x1.w;
            }
            *(f16x8*)&As[sr * 40 + sq * 8] = av;

            const float4* pw = (const float4*)&Wp[(size_t)(nBase + sr) * 1024 + k0 + sq * 8];
            float4 w0 = pw[0], w1 = pw[1];
            f16x8 bv;
            bv[0] = (f16)w0.x; bv[1] = (f16)w0.y; bv[2] = (f16)w0.z; bv[3] = (f16)w0.w;
            bv[4] = (f16)w1.x; bv[5] = (f16)w1.y; bv[6] = (f16)w1.z; bv[7] = (f16)w1.w;
            *(f16x8*)&Bs[sr * 40 + sq * 8] = bv;
        }
        __syncthreads();

        f16x8 af[2], bf[4];
#pragma unroll
        for (int mt = 0; mt < 2; mt++)
            af[mt] = *(const f16x8*)&As[(wm * 32 + mt * 16 + c) * 40 + g * 8];
#pragma unroll
        for (int nt = 0; nt < 4; nt++)
            bf[nt] = *(const f16x8*)&Bs[(wn * 64 + nt * 16 + c) * 40 + g * 8];
#pragma unroll
        for (int mt = 0; mt < 2; mt++)
#pragma unroll
            for (int nt = 0; nt < 4; nt++)
                acc[mt][nt] = __builtin_amdgcn_mfma_f32_16x16x32_f16(af[mt], bf[nt], acc[mt][nt], 0, 0, 0);
    }

#pragma unroll
    for (int mt = 0; mt < 2; mt++)
#pragma unroll
        for (int nt = 0; nt < 4; nt++) {
            int row0 = mBase + wm * 32 + mt * 16 + g * 4;      // + r
            int col = nBase + wn * 64 + nt * 16 + c;
            if constexpr (MODE == 3) {
#pragma unroll
                for (int r = 0; r < 4; r++)
                    ((float*)Cp)[(size_t)(row0 + r) * 1024 + col] = acc[mt][nt][r];
            } else if constexpr (MODE == 2) {
                int b = row0 >> 11, l0 = row0 & 2047;
                int h = col >> 6, dk = col & 63;
                f16x4 pv;
#pragma unroll
                for (int r = 0; r < 4; r++) pv[r] = (f16)acc[mt][nt][r];
                *(f16x4*)&((f16*)Cp)[((size_t)(b * 16 + h) * 64 + dk) * 2048 + l0] = pv;
            } else {
#pragma unroll
                for (int r = 0; r < 4; r++) {
                    int row = row0 + r;
                    float v = acc[mt][nt][r];
                    if constexpr (MODE == 0) v *= 0.0625f;     // 1/sqrt(64) * 1/2
                    int b = row >> 11, l = row & 2047;
                    int h = col >> 6, dk = col & 63;
                    ((f16*)Cp)[((size_t)(b * 16 + h) * 2048 + l) * 64 + dk] = (f16)v;
                }
            }
        }
}

// ---------------------------------------------------------------------------
// Attention + exact 1.5-entmax, swapped-operand layout.
// Block = 16 queries x 2048 keys, 8 waves; wave w owns keys [w*256, w*256+256).
// Lane (g = lane>>4, c = lane&15): holds S^T values for query (qb+c),
// keys {w*256 + t*16 + g*4 + r}. tau solves sum((z - tau)_+^2) = 1.
// ---------------------------------------------------------------------------
__global__ __launch_bounds__(512, 4)
void attn_entmax(const f16* __restrict__ Q, const f16* __restrict__ Kh,
                 const f16* __restrict__ Vt, const u32* __restrict__ mbits,
                 f16* __restrict__ AO)
{
    __shared__ float red[2][8][16][2];               // double-buffered Newton reduce
    __shared__ float redS[8][16][4];                 // support pass (kc, s1, s2)
    __shared__ __align__(16) float Ored[8 * 16 * 68];// O partials, rows padded to 68

    const int tid = threadIdx.x;
    const int w = tid >> 6, lane = tid & 63;
    const int g = lane >> 4, c = lane & 15;
    const int bh = blockIdx.y, b = bh >> 4, h = bh & 15;
    const int qb = blockIdx.x * 16;
    const int kbase = w * 256;

    // Q B-fragments (col = query = c, k-dim = d)
    const f16* qp = &Q[(size_t)(bh * 2048 + qb + c) * 64 + g * 8];
    f16x8 bq0 = *(const f16x8*)qp;
    f16x8 bq1 = *(const f16x8*)(qp + 32);

    // ---- scores S^T: mfma(A=K rows=keys, B=Q cols=queries) ----
    f32x4 S[16];
    const f32x4 vz = {0.f, 0.f, 0.f, 0.f};
#pragma unroll
    for (int t = 0; t < 16; t++) {
        const f16* kp = &Kh[(size_t)(bh * 2048 + kbase + t * 16 + c) * 64 + g * 8];
        f16x8 ka0 = *(const f16x8*)kp;
        f16x8 ka1 = *(const f16x8*)(kp + 32);
        f32x4 z = __builtin_amdgcn_mfma_f32_16x16x32_f16(ka0, bq0, vz, 0, 0, 0);
        S[t] = __builtin_amdgcn_mfma_f32_16x16x32_f16(ka1, bq1, z, 0, 0, 0);
    }

    // ---- mask via packed bits: lane's keys are kbase + t*16 + g*4 + r ----
    {
        const uint4* mp = (const uint4*)&mbits[(size_t)(b * 2048 + qb + c) * 64 + w * 8];
        uint4 mA = mp[0], mB = mp[1];
        u32 mb[8] = {mA.x, mA.y, mA.z, mA.w, mB.x, mB.y, mB.z, mB.w};
#pragma unroll
        for (int t = 0; t < 16; t++) {
            u32 b4 = mb[t >> 1] >> ((t & 1) * 16 + g * 4);
#pragma unroll
            for (int r = 0; r < 4; r++)
                if (!((b4 >> r) & 1)) S[t][r] = -1e30f;
        }
    }

    // ---- global zmax for this lane's query ----
    float zx = -3e38f;
#pragma unroll
    for (int t = 0; t < 16; t++)
#pragma unroll
        for (int r = 0; r < 4; r++) zx = fmaxf(zx, S[t][r]);
    zx = fmaxf(zx, __shfl_xor(zx, 16));
    zx = fmaxf(zx, __shfl_xor(zx, 32));
    if (lane < 16) red[0][w][c][0] = zx;
    __syncthreads();
    float zmax = -3e38f;
#pragma unroll
    for (int ww = 0; ww < 8; ww++) zmax = fmaxf(zmax, red[0][ww][c][0]);

    // ---- Newton from below: tau0 = zmax - 1, f(tau) = sum((z-tau)_+^2) ----
    float tau = zmax - 1.0f;
    int buf = 1;
#pragma unroll 1
    for (int it = 0; it < 8; ++it) {
        float s1 = 0.f, s2 = 0.f;
#pragma unroll
        for (int t = 0; t < 16; t++)
#pragma unroll
            for (int r = 0; r < 4; r++) {
                float d = fmaxf(S[t][r] - tau, 0.f);
                s1 += d;
                s2 = fmaf(d, d, s2);
            }
        s1 += __shfl_xor(s1, 16); s1 += __shfl_xor(s1, 32);
        s2 += __shfl_xor(s2, 16); s2 += __shfl_xor(s2, 32);
        if (lane < 16) { red[buf][w][c][0] = s1; red[buf][w][c][1] = s2; }
        __syncthreads();
        float a = 0.f, f = 0.f;
#pragma unroll
        for (int ww = 0; ww < 8; ww++) {
            float2 v = *(const float2*)&red[buf][ww][c][0];
            a += v.x; f += v.y;
        }
        if (a > 1e-12f)
            tau = fminf(tau + (f - 1.0f) / (2.0f * a), zmax - 1e-3f);
        buf ^= 1;
    }

    // ---- closed-form refine over support {z > tau} ----
    {
        float kc = 0.f, s1 = 0.f, s2 = 0.f;
#pragma unroll
        for (int t = 0; t < 16; t++)
#pragma unroll
            for (int r = 0; r < 4; r++) {
                float d = S[t][r] - tau;
                if (d > 0.f) { kc += 1.f; s1 += d; s2 = fmaf(d, d, s2); }
            }
        kc += __shfl_xor(kc, 16); kc += __shfl_xor(kc, 32);
        s1 += __shfl_xor(s1, 16); s1 += __shfl_xor(s1, 32);
        s2 += __shfl_xor(s2, 16); s2 += __shfl_xor(s2, 32);
        if (lane < 16) {
            redS[w][c][0] = kc; redS[w][c][1] = s1; redS[w][c][2] = s2; redS[w][c][3] = 0.f;
        }
        __syncthreads();
        float K_ = 0.f, a = 0.f, q2 = 0.f;
#pragma unroll
        for (int ww = 0; ww < 8; ww++) {
            float4 v = *(const float4*)&redS[ww][c][0];
            K_ += v.x; a += v.y; q2 += v.z;
        }
        K_ = fmaxf(K_, 1.0f);
        float disc = fmaxf(a * a - K_ * (q2 - 1.0f), 0.f);
        tau += (a - sqrtf(disc)) / K_;
    }

    // ---- P = ((z-tau)_+)^2 in regs -> PV via mfma 16x16x16 (B-frag == D-frag) ----
    f32x4 O[4];
#pragma unroll
    for (int nd = 0; nd < 4; nd++) O[nd] = vz;
#pragma unroll
    for (int t = 0; t < 16; t++) {
        f16x4 pf;
#pragma unroll
        for (int r = 0; r < 4; r++) {
            float d = fmaxf(S[t][r] - tau, 0.f);
            pf[r] = (f16)(d * d);
        }
        const int j0 = kbase + t * 16;
#pragma unroll
        for (int nd = 0; nd < 4; nd++) {
            f16x4 va = *(const f16x4*)&Vt[(size_t)(bh * 64 + nd * 16 + c) * 2048 + j0 + g * 4];
            O[nd] = __builtin_amdgcn_mfma_f32_16x16x16f16(va, pf, O[nd], 0, 0, 0);
        }
    }

    // ---- cross-wave O reduction ----
#pragma unroll
    for (int nd = 0; nd < 4; nd++)
        *(f32x4*)&Ored[(w * 16 + c) * 68 + nd * 16 + g * 4] = O[nd];
    __syncthreads();

    const int qrow = tid >> 5;   // 0..15
    const int dp = tid & 31;     // 0..31 (pairs of d)
    float o0 = 0.f, o1 = 0.f;
#pragma unroll
    for (int ww = 0; ww < 8; ww++) {
        float2 v = *(const float2*)&Ored[(ww * 16 + qrow) * 68 + dp * 2];
        o0 += v.x; o1 += v.y;
    }
    f16x2 pk;
    pk[0] = (f16)o0;
    pk[1] = (f16)o1;
    *(f16x2*)&AO[(size_t)(b * 2048 + qb + qrow) * 1024 + h * 64 + dp * 2] = pk;
}

// ---------------------------------------------------------------------------
extern "C" void kernel_launch(void* const* d_in, const int* in_sizes, int n_in,
                              void* d_out, int out_size, void* d_ws, size_t ws_size,
                              hipStream_t stream)
{
    const float* q  = (const float*)d_in[0];
    const float* k  = (const float*)d_in[1];
    const float* v  = (const float*)d_in[2];
    const int* mask = (const int*)d_in[3];
    const float* wq = (const float*)d_in[4];
    const float* wk = (const float*)d_in[5];
    const float* wv = (const float*)d_in[6];
    const float* wo = (const float*)d_in[7];

    char* ws = (char*)d_ws;
    const size_t SZ = 8388608ull;            // 8 MB per f16 buffer
    f16* Qb  = (f16*)(ws);
    f16* Kb  = (f16*)(ws + SZ);
    f16* Vtb = (f16*)(ws + 2 * SZ);
    f16* AOb = (f16*)(ws + 3 * SZ);
    u32* Mb  = (u32*)(ws + 4 * SZ);          // 1 MB packed mask

    pack_mask<<<1024, 256, 0, stream>>>(mask, Mb);

    dim3 gg(32, 8);
    gemm_proj<0><<<gg, 512, 0, stream>>>(q, wq, Qb);
    gemm_proj<1><<<gg, 512, 0, stream>>>(k, wk, Kb);
    gemm_proj<2><<<gg, 512, 0, stream>>>(v, wv, Vtb);
    attn_entmax<<<dim3(128, 32), 512, 0, stream>>>(Qb, Kb, Vtb, Mb, AOb);
    gemm_proj<3><<<gg, 512, 0, stream>>>(AOb, wo, d_out);
}